// Round 9
// baseline (418.071 us; speedup 1.0000x reference)
//
#include <hip/hip_runtime.h>
#include <hip/hip_bf16.h>
#include <math.h>

#define BATCH 2
#define NPT   8192
#define DIMC  128
#define NH    4
#define KNN_K 16
#define HID   32
#define BN    (BATCH*NPT)   // 16384

// ===========================================================================
// KNN via exact uniform-grid search.
// Grid 32^3 over [-4,4]^3 (cs=0.25). Points stored CSR-style per cell as
// (2x,2y,2z,sq) — doubling is exact, so d2 = (qsq+sq) - dot2 is bit-identical
// to numpy's sq_i+sq_j-2*dot. Query expands Chebyshev shells; after shell r,
// any unseen point is >= r*cs away (minus 1e-5 slop margin for cell-assign
// rounding), so stop when (r*cs-1e-5)^2 > tau. Scatter order is
// nondeterministic (atomics), so top-16 selection is LEXICOGRAPHIC on
// (d2, idx): order-independent, duplicates impossible (shells disjoint),
// ties = lowest index = jax.lax.top_k semantics. Output deterministic.
// ===========================================================================
#define GRID_N 32
#define NCELL  (GRID_N*GRID_N*GRID_N)
#define GLO   -4.0f
#define GCS    0.25f
#define GINV   4.0f

__device__ __forceinline__ float readlane_f(float v, int l) {
  return __int_as_float(__builtin_amdgcn_readlane(__float_as_int(v), l));
}
__device__ __forceinline__ int clampi(int v, int lo, int hi) {
  return v < lo ? lo : (v > hi ? hi : v);
}
__device__ __forceinline__ int cell_of(float x, float y, float z) {
  const int cx = clampi((int)floorf((x - GLO)*GINV), 0, GRID_N-1);
  const int cy = clampi((int)floorf((y - GLO)*GINV), 0, GRID_N-1);
  const int cz = clampi((int)floorf((z - GLO)*GINV), 0, GRID_N-1);
  return (cz*GRID_N + cy)*GRID_N + cx;
}

__global__ __launch_bounds__(256) void zero_kernel(int* __restrict__ c) {
  const int i = blockIdx.x*256 + threadIdx.x;
  if (i < 2*NCELL) c[i] = 0;
}

__global__ __launch_bounds__(256) void count_kernel(const float* __restrict__ xyz,
                                                    int* __restrict__ counts) {
  const int i = blockIdx.x*256 + threadIdx.x;   // 0..BN-1
  const float x = xyz[(size_t)i*3+0], y = xyz[(size_t)i*3+1], z = xyz[(size_t)i*3+2];
  const int b = i >> 13;
  atomicAdd(&counts[b*NCELL + cell_of(x,y,z)], 1);
}

__global__ __launch_bounds__(1024) void scan_kernel(const int* __restrict__ counts,
                                                    int* __restrict__ starts,
                                                    int* __restrict__ cursor) {
  __shared__ int sd[1024];
  const int t = threadIdx.x;
  for (int b = 0; b < 2; ++b) {
    const int* c = counts + b*NCELL;
    int* s  = starts + b*(NCELL+1);
    int* cu = cursor + b*NCELL;
    int loc[32]; int sum = 0;
#pragma unroll
    for (int j = 0; j < 32; ++j) { loc[j] = sum; sum += c[t*32 + j]; }
    __syncthreads();           // protect sd reuse across batches
    sd[t] = sum;
    __syncthreads();
    for (int off = 1; off < 1024; off <<= 1) {
      const int u = (t >= off) ? sd[t-off] : 0;
      __syncthreads();
      sd[t] += u;
      __syncthreads();
    }
    const int excl = sd[t] - sum;
#pragma unroll
    for (int j = 0; j < 32; ++j) { s[t*32+j] = excl + loc[j]; cu[t*32+j] = excl + loc[j]; }
    if (t == 1023) s[NCELL] = sd[1023];   // = 8192
  }
}

__global__ __launch_bounds__(256) void scatter_kernel(const float* __restrict__ xyz,
    int* __restrict__ cursor, float4* __restrict__ pts4, int* __restrict__ pidx) {
  const int i = blockIdx.x*256 + threadIdx.x;
  const float x = xyz[(size_t)i*3+0], y = xyz[(size_t)i*3+1], z = xyz[(size_t)i*3+2];
  const int b = i >> 13;
  const float sq = __fadd_rn(__fadd_rn(__fmul_rn(x,x), __fmul_rn(y,y)),
                             __fmul_rn(z,z));
  const int slot = atomicAdd(&cursor[b*NCELL + cell_of(x,y,z)], 1);
  pts4[b*NPT + slot] = make_float4(x+x, y+y, z+z, sq);
  pidx[b*NPT + slot] = i & (NPT-1);   // within-batch index
}

// one wave per query; top-16 distributed over lanes 0..15, ascending lex
__global__ __launch_bounds__(256) void knn_query_kernel(const float* __restrict__ xyz,
    const int* __restrict__ starts, const float4* __restrict__ pts4,
    const int* __restrict__ pidx, int* __restrict__ knn_out) {
  const int tid = threadIdx.x, lane = tid & 63, wave = tid >> 6;
  const int p = blockIdx.x*4 + wave;
  const int b = p >> 13;
  const float qx = xyz[(size_t)p*3+0], qy = xyz[(size_t)p*3+1], qz = xyz[(size_t)p*3+2];
  const float qsq = __fadd_rn(__fadd_rn(__fmul_rn(qx,qx), __fmul_rn(qy,qy)),
                              __fmul_rn(qz,qz));
  const int cx = clampi((int)floorf((qx - GLO)*GINV), 0, GRID_N-1);
  const int cy = clampi((int)floorf((qy - GLO)*GINV), 0, GRID_N-1);
  const int cz = clampi((int)floorf((qz - GLO)*GINV), 0, GRID_N-1);
  const int*    sb = starts + b*(NCELL+1);
  const float4* pb = pts4 + (size_t)b*NPT;
  const int*    ib = pidx + (size_t)b*NPT;

  float topd = INFINITY; int topi = 0x7fffffff;
  float tau  = INFINITY; int taui = 0x7fffffff;

  auto process = [&](int beg, int end) {
    for (int c0 = beg; c0 < end; c0 += 64) {
      const int ci = c0 + lane;
      float d2 = INFINITY; int di = 0x7fffffff;
      if (ci < end) {
        const float4 cd = pb[ci];
        const float dot2 = __fadd_rn(__fadd_rn(__fmul_rn(qx,cd.x),
                                               __fmul_rn(qy,cd.y)),
                                     __fmul_rn(qz,cd.z));
        d2 = __fsub_rn(__fadd_rn(qsq, cd.w), dot2);
        di = ib[ci];
      }
      unsigned long long m = __ballot((d2 < tau) | (d2 == tau && di < taui));
      while (m) {
        const int l = (int)__builtin_ctzll(m);
        const float dn  = readlane_f(d2, l);
        const int   dni = __builtin_amdgcn_readlane(di, l);
        const float my  = topd; const int myi = topi;
        float ab  = __shfl_up(my, 1);
        int   abi = __shfl_up(myi, 1);
        if (lane == 0) { ab = -INFINITY; abi = -1; }
        const bool ge = (dn < my) | (dn == my && dni < myi);
        const bool gt = (dn < ab) | (dn == ab && dni < abi);
        topd = ge ? (gt ? ab  : dn ) : my;
        topi = ge ? (gt ? abi : dni) : myi;
        tau  = readlane_f(topd, 15);
        taui = __builtin_amdgcn_readlane(topi, 15);
        m &= (m - 1);
        if (m) m &= __ballot((d2 < tau) | (d2 == tau && di < taui));
      }
    }
  };

  for (int r = 0; r < GRID_N; ++r) {
    const int zlo = clampi(cz-r, 0, GRID_N-1), zhi = clampi(cz+r, 0, GRID_N-1);
    const int ylo = clampi(cy-r, 0, GRID_N-1), yhi = clampi(cy+r, 0, GRID_N-1);
    const int xlo = clampi(cx-r, 0, GRID_N-1), xhi = clampi(cx+r, 0, GRID_N-1);
    for (int z = zlo; z <= zhi; ++z) {
      const bool ze = (z == cz-r) || (z == cz+r);
      for (int y = ylo; y <= yhi; ++y) {
        const bool ye = (y == cy-r) || (y == cy+r);
        const int cb = (z*GRID_N + y)*GRID_N;
        if (ze || ye) {
          process(sb[cb+xlo], sb[cb+xhi+1]);        // full x-run (contiguous)
        } else {                                     // interior: two x caps
          if (cx-r >= 0)       process(sb[cb+cx-r], sb[cb+cx-r+1]);
          if (cx+r <= GRID_N-1) process(sb[cb+cx+r], sb[cb+cx+r+1]);
        }
      }
    }
    const float rb = (float)r*GCS - 1e-5f;   // dist bound to shell r+1
    if (rb > 0.f && rb*rb > tau) break;
  }

  if (lane < KNN_K) knn_out[(size_t)p*KNN_K + lane] = topi;
}

// ---------------------------------------------------------------------------
// float4-component extract (u is compile-time constant in unrolled loops)
// ---------------------------------------------------------------------------
__device__ __forceinline__ float f4c(const float4 v, int u) {
  return u == 0 ? v.x : u == 1 ? v.y : u == 2 ? v.z : v.w;
}

// ---------------------------------------------------------------------------
// Kernel 2: fused Q/K/V projection, 8-rows-per-thread register blocking.
// (unchanged from round 8)
// ---------------------------------------------------------------------------
#define QKV_ROWS 32

__global__ __launch_bounds__(128) void qkv_kernel(const float* __restrict__ x,
    const float* __restrict__ Wq, const float* __restrict__ bq,
    const float* __restrict__ Wk, const float* __restrict__ bk,
    const float* __restrict__ Wv, const float* __restrict__ bv,
    float* __restrict__ q, float* __restrict__ k, float* __restrict__ v) {
  __shared__ float xs[QKV_ROWS*DIMC];   // 16 KB
  const int tid = threadIdx.x;
  const int rowbase = blockIdx.x * QKV_ROWS;
  {
    float4* xs4 = (float4*)xs;
    const float4* src4 = (const float4*)(x + (size_t)rowbase*DIMC);
    for (int i = tid; i < QKV_ROWS*DIMC/4; i += 128) xs4[i] = src4[i];
  }
  __syncthreads();

  const int cg = tid & 31, rg = tid >> 5;   // rg 0..3
  const int c0 = cg * 4;
  float4 aq[8], ak[8], av[8];
  {
    const float4 bq4 = *(const float4*)&bq[c0];
    const float4 bk4 = *(const float4*)&bk[c0];
    const float4 bv4 = *(const float4*)&bv[c0];
#pragma unroll
    for (int i = 0; i < 8; ++i) { aq[i] = bq4; ak[i] = bk4; av[i] = bv4; }
  }

  for (int kk = 0; kk < DIMC; kk += 4) {
    float4 xr[8];
#pragma unroll
    for (int i = 0; i < 8; ++i)
      xr[i] = *(const float4*)&xs[(rg + 4*i)*DIMC + kk];
#pragma unroll
    for (int u = 0; u < 4; ++u) {
      const float4 wq = *(const float4*)&Wq[(size_t)(kk+u)*DIMC + c0];
      const float4 wk = *(const float4*)&Wk[(size_t)(kk+u)*DIMC + c0];
      const float4 wv = *(const float4*)&Wv[(size_t)(kk+u)*DIMC + c0];
#pragma unroll
      for (int i = 0; i < 8; ++i) {
        const float xv = f4c(xr[i], u);
        aq[i].x = fmaf(xv, wq.x, aq[i].x); aq[i].y = fmaf(xv, wq.y, aq[i].y);
        aq[i].z = fmaf(xv, wq.z, aq[i].z); aq[i].w = fmaf(xv, wq.w, aq[i].w);
        ak[i].x = fmaf(xv, wk.x, ak[i].x); ak[i].y = fmaf(xv, wk.y, ak[i].y);
        ak[i].z = fmaf(xv, wk.z, ak[i].z); ak[i].w = fmaf(xv, wk.w, ak[i].w);
        av[i].x = fmaf(xv, wv.x, av[i].x); av[i].y = fmaf(xv, wv.y, av[i].y);
        av[i].z = fmaf(xv, wv.z, av[i].z); av[i].w = fmaf(xv, wv.w, av[i].w);
      }
    }
  }

#pragma unroll
  for (int i = 0; i < 8; ++i) {
    const size_t rr = (size_t)(rowbase + rg + 4*i)*DIMC + c0;
    *(float4*)&q[rr] = aq[i];
    *(float4*)&k[rr] = ak[i];
    *(float4*)&v[rr] = av[i];
  }
}

// ---------------------------------------------------------------------------
// DPP ring-rotate move (VALU, no DS pipe): lane i of each 16-lane row reads
// lane (i+N)%16. Ring all-reduce with N=1,2,4,8 covers all 16 lanes.
// ---------------------------------------------------------------------------
template <int CTRL>
__device__ __forceinline__ float dppf(float x) {
  return __int_as_float(__builtin_amdgcn_update_dpp(
      __float_as_int(x), __float_as_int(x), CTRL, 0xF, 0xF, false));
}
#define ROR1 0x121
#define ROR2 0x122
#define ROR4 0x124
#define ROR8 0x128

// ---------------------------------------------------------------------------
// Kernel 3: gather + bias MLP + attention. ONE WAVE PER POINT. (unchanged)
// ---------------------------------------------------------------------------
__global__ __launch_bounds__(256) void attn_kernel(const float* __restrict__ xyz,
    const int* __restrict__ knn, const float* __restrict__ qb,
    const float* __restrict__ kb, const float* __restrict__ vb,
    const float* __restrict__ W1, const float* __restrict__ b1,
    const float* __restrict__ W2, const float* __restrict__ b2,
    float* __restrict__ ao) {
  __shared__ float sw[4][NH][KNN_K];
  __shared__ int   sn[4][KNN_K];
  const int tid  = threadIdx.x;
  const int wave = tid >> 6;
  const int lane = tid & 63;
  const int p = blockIdx.x * 4 + wave;
  const int b = p / NPT;
  const int h = lane >> 4;
  const int j = lane & 15;

  const int nj = knn[(size_t)p*KNN_K + j];
  if (h == 0) sn[wave][j] = nj;
  const size_t nn = (size_t)b*NPT + nj;

  // bias MLP for this lane's (h, j)
  const float qx0 = xyz[(size_t)p*3+0];
  const float qy0 = xyz[(size_t)p*3+1];
  const float qz0 = xyz[(size_t)p*3+2];
  const float rx = qx0 - xyz[nn*3+0];
  const float ry = qy0 - xyz[nn*3+1];
  const float rz = qz0 - xyz[nn*3+2];
  float bias = b2[h];
#pragma unroll 8
  for (int u = 0; u < HID; ++u) {
    float hv = rx*W1[0*HID+u] + ry*W1[1*HID+u] + rz*W1[2*HID+u] + b1[u];
    hv = hv > 0.f ? hv : 0.f;
    bias = fmaf(hv, W2[u*NH + h], bias);
  }

  // score: q[p,h,:] · k[nj,h,:]  (32 channels, 8x float4 each side)
  const float* qrow = qb + (size_t)p*DIMC + h*32;
  const float* krow = kb + nn*DIMC + h*32;
  float s = 0.f;
#pragma unroll
  for (int u = 0; u < 32; u += 4) {
    const float4 qv = *(const float4*)(qrow + u);
    const float4 kv = *(const float4*)(krow + u);
    s = fmaf(qv.x, kv.x, s); s = fmaf(qv.y, kv.y, s);
    s = fmaf(qv.z, kv.z, s); s = fmaf(qv.w, kv.w, s);
  }
  s = s * 0.17677669529663689f + bias;   // 1/sqrt(32)

  // softmax over the 16-lane j-group: DPP ring all-reduce (max, then sum)
  float m = s;
  m = fmaxf(m, dppf<ROR1>(m));
  m = fmaxf(m, dppf<ROR2>(m));
  m = fmaxf(m, dppf<ROR4>(m));
  m = fmaxf(m, dppf<ROR8>(m));
  const float e = expf(s - m);
  float ssum = e;
  ssum += dppf<ROR1>(ssum);
  ssum += dppf<ROR2>(ssum);
  ssum += dppf<ROR4>(ssum);
  ssum += dppf<ROR8>(ssum);
  sw[wave][h][j] = e / ssum;

  __syncthreads();

  // phase B: lane = channel d0 (and d0+64); weighted sum of v rows
  const int d0 = lane;
  const int hA = d0 >> 5;              // head of channel d0 (0 or 1)
  float out0 = 0.f, out1 = 0.f;
  const float* vbase = vb + (size_t)b*NPT*DIMC;
#pragma unroll 4
  for (int j2 = 0; j2 < KNN_K; ++j2) {
    const int n = sn[wave][j2];
    const float wA = sw[wave][hA][j2];
    const float wB = sw[wave][2+hA][j2];
    const float* vrow = vbase + (size_t)n*DIMC;
    out0 = fmaf(wA, vrow[d0],    out0);
    out1 = fmaf(wB, vrow[64+d0], out1);
  }
  ao[(size_t)p*DIMC + d0]      = out0;
  ao[(size_t)p*DIMC + 64 + d0] = out1;
}

// ---------------------------------------------------------------------------
// Kernel 4: output projection, 8-rows-per-thread register blocking,
// IN-PLACE on d_out (block stages its own 32 rows first — no hazard).
// (unchanged)
// ---------------------------------------------------------------------------
__global__ __launch_bounds__(128) void proj_kernel(float* __restrict__ inout,
    const float* __restrict__ Wo, const float* __restrict__ bo) {
  __shared__ float xs[QKV_ROWS*DIMC];   // 16 KB
  const int tid = threadIdx.x;
  const int rowbase = blockIdx.x * QKV_ROWS;
  {
    float4* xs4 = (float4*)xs;
    const float4* src4 = (const float4*)(inout + (size_t)rowbase*DIMC);
    for (int i = tid; i < QKV_ROWS*DIMC/4; i += 128) xs4[i] = src4[i];
  }
  __syncthreads();

  const int cg = tid & 31, rg = tid >> 5;   // rg 0..3
  const int c0 = cg * 4;
  float4 a[8];
  {
    const float4 bo4 = *(const float4*)&bo[c0];
#pragma unroll
    for (int i = 0; i < 8; ++i) a[i] = bo4;
  }

  for (int kk = 0; kk < DIMC; kk += 4) {
    float4 xr[8];
#pragma unroll
    for (int i = 0; i < 8; ++i)
      xr[i] = *(const float4*)&xs[(rg + 4*i)*DIMC + kk];
#pragma unroll
    for (int u = 0; u < 4; ++u) {
      const float4 w = *(const float4*)&Wo[(size_t)(kk+u)*DIMC + c0];
#pragma unroll
      for (int i = 0; i < 8; ++i) {
        const float xv = f4c(xr[i], u);
        a[i].x = fmaf(xv, w.x, a[i].x); a[i].y = fmaf(xv, w.y, a[i].y);
        a[i].z = fmaf(xv, w.z, a[i].z); a[i].w = fmaf(xv, w.w, a[i].w);
      }
    }
  }

#pragma unroll
  for (int i = 0; i < 8; ++i)
    *(float4*)&inout[(size_t)(rowbase + rg + 4*i)*DIMC + c0] = a[i];
}

// ---------------------------------------------------------------------------
extern "C" void kernel_launch(void* const* d_in, const int* in_sizes, int n_in,
                              void* d_out, int out_size, void* d_ws, size_t ws_size,
                              hipStream_t stream) {
  const float* x   = (const float*)d_in[0];
  const float* xyz = (const float*)d_in[1];
  const float* Wq  = (const float*)d_in[2];
  const float* bq  = (const float*)d_in[3];
  const float* Wk  = (const float*)d_in[4];
  const float* bk  = (const float*)d_in[5];
  const float* Wv  = (const float*)d_in[6];
  const float* bv  = (const float*)d_in[7];
  const float* Wo  = (const float*)d_in[8];
  const float* bo  = (const float*)d_in[9];
  const float* W1  = (const float*)d_in[10];
  const float* b1  = (const float*)d_in[11];
  const float* W2  = (const float*)d_in[12];
  const float* b2  = (const float*)d_in[13];
  float* out = (float*)d_out;

  // workspace layout (bytes):
  //   [0,1MB)   knn idx
  //   [1MB,9MB) q   — grid-build arrays live here transiently (dead before
  //                   qkv_kernel writes q; stream order guarantees safety)
  //   [9MB,17MB)  k
  //   [17MB,25MB) v
  char* ws = (char*)d_ws;
  int*    knn    = (int*)ws;
  char*   g      = ws + (1u<<20);
  int*    counts = (int*)g;                       // 256 KB
  int*    starts = (int*)(g + 256*1024);          // 256 KB + 8
  int*    cursor = (int*)(g + 576*1024);          // 256 KB
  float4* pts4   = (float4*)(g + 832*1024);       // 256 KB
  int*    pidx   = (int*)(g + 1088*1024);         //  64 KB
  float*  q      = (float*)(ws + (size_t)(1u<<20));
  float*  k      = (float*)(ws + (size_t)9*(1u<<20));
  float*  v      = (float*)(ws + (size_t)17*(1u<<20));

  hipLaunchKernelGGL(zero_kernel,  dim3((2*NCELL+255)/256), dim3(256), 0, stream, counts);
  hipLaunchKernelGGL(count_kernel, dim3(BN/256), dim3(256), 0, stream, xyz, counts);
  hipLaunchKernelGGL(scan_kernel,  dim3(1), dim3(1024), 0, stream, counts, starts, cursor);
  hipLaunchKernelGGL(scatter_kernel, dim3(BN/256), dim3(256), 0, stream, xyz, cursor, pts4, pidx);
  hipLaunchKernelGGL(knn_query_kernel, dim3(BN/4), dim3(256), 0, stream,
                     xyz, starts, pts4, pidx, knn);
  hipLaunchKernelGGL(qkv_kernel, dim3(BN/QKV_ROWS), dim3(128), 0, stream,
                     x, Wq, bq, Wk, bk, Wv, bv, q, k, v);
  hipLaunchKernelGGL(attn_kernel, dim3(BN/4), dim3(256), 0, stream,
                     xyz, knn, q, k, v, W1, b1, W2, b2, out);
  hipLaunchKernelGGL(proj_kernel, dim3(BN/QKV_ROWS), dim3(128), 0, stream,
                     out, Wo, bo);
}